// Round 7
// baseline (319.563 us; speedup 1.0000x reference)
//
#include <hip/hip_runtime.h>
#include <cstdint>
#include <cmath>

// Problem constants
constexpr int TT   = 256;   // tokens
constexpr int HD   = 1024;  // hidden
constexpr int IDIM = 512;   // intermediate
constexpr int NE   = 32;    // experts
constexpr int NGRP = 8;
constexpr int TKG  = 4;
constexpr int TOPK = 8;
constexpr float RSCALE = 2.5f;

constexpr int NSX  = HD / 32;     // 32 k-slabs in Xe
constexpr int NSA  = IDIM / 32;   // 16 k-slabs in A
constexpr int SLAB = 16 * 64 * 8; // halves per (expert, slab): 16 mt-tiles x 64 lanes x 8

typedef float    f32x4 __attribute__((ext_vector_type(4)));
typedef _Float16 half8 __attribute__((ext_vector_type(8)));

// Workspace layout (bytes)
constexpr size_t WS_CNT = 0;                              // NE ints (zeroed)
constexpr size_t WS_TOK = 256;                            // NE*TT ints
constexpr size_t WS_WL  = WS_TOK + (size_t)NE * TT * 4;   // NE*TT floats
constexpr size_t WS_XE  = WS_WL  + (size_t)NE * TT * 4;   // NE*NSX*SLAB f16 (16 MB), frag-swizzled x
constexpr size_t WS_A   = WS_XE  + (size_t)NE * NSX * SLAB * 2; // NE*NSA*SLAB f16 (8 MB)

// ---------------- Routing (unchanged) ----------------
__global__ __launch_bounds__(256) void k_route(
    const float* __restrict__ x, const float* __restrict__ gw,
    const float* __restrict__ bias, int* __restrict__ cnt,
    int* __restrict__ tok, float* __restrict__ wl)
{
    int t = blockIdx.x;
    int tid = threadIdx.x;
    int e2 = (tid & 15) * 2;
    int c  = tid >> 4;
    const float* xr = x + (size_t)t * HD;

    float a0 = 0.f, a1 = 0.f;
    int h0 = c * (HD / 16);
#pragma unroll 8
    for (int h = h0; h < h0 + HD / 16; ++h) {
        float xv = xr[h];
        float2 wv = *(const float2*)&gw[(size_t)h * NE + e2];
        a0 += xv * wv.x;
        a1 += xv * wv.y;
    }

    __shared__ float part[16][NE];
    part[c][e2]     = a0;
    part[c][e2 + 1] = a1;
    __syncthreads();

    __shared__ float sc[NE], sfc[NE];
    if (tid < NE) {
        float s = 0.f;
#pragma unroll
        for (int cc = 0; cc < 16; ++cc) s += part[cc][tid];
        float sig = 1.f / (1.f + expf(-s));
        sc[tid]  = sig;
        sfc[tid] = sig + bias[tid];
    }
    __syncthreads();

    if (tid == 0) {
        float gs[NGRP];
        for (int g = 0; g < NGRP; ++g) {
            float m1 = -3.0e38f, m2 = -3.0e38f;
            for (int j = 0; j < 4; ++j) {
                float v = sfc[4 * g + j];
                if (v > m1) { m2 = m1; m1 = v; } else if (v > m2) m2 = v;
            }
            gs[g] = m1 + m2;
        }
        bool gsel[NGRP];
        for (int g = 0; g < NGRP; ++g) gsel[g] = false;
        for (int r = 0; r < TKG; ++r) {
            int bi = -1; float bv = -3.0e38f;
            for (int g = 0; g < NGRP; ++g)
                if (!gsel[g] && gs[g] > bv) { bv = gs[g]; bi = g; }
            gsel[bi] = true;
        }
        float masked[NE];
        for (int i = 0; i < NE; ++i) masked[i] = gsel[i >> 2] ? sfc[i] : 0.0f;
        int   idx[TOPK]; float wv[TOPK]; float wsum = 0.f;
        for (int r = 0; r < TOPK; ++r) {
            int bi = -1; float bv = -3.0e38f;
            for (int i = 0; i < NE; ++i)
                if (masked[i] > bv) { bv = masked[i]; bi = i; }
            masked[bi] = -3.0e38f;
            idx[r] = bi; wv[r] = sc[bi]; wsum += wv[r];
        }
        float inv = RSCALE / (wsum + 1e-20f);
        for (int r = 0; r < TOPK; ++r) {
            int ee = idx[r];
            int pos = atomicAdd(&cnt[ee], 1);
            tok[(size_t)ee * TT + pos] = t;
            wl [(size_t)ee * TT + pos] = wv[r] * inv;
        }
    }
}

// ---------------- Pack: gather x rows into MFMA-A-fragment slabs ----------------
__global__ __launch_bounds__(256) void k_pack(
    const float* __restrict__ x, const int* __restrict__ cnt,
    const int* __restrict__ tok, _Float16* __restrict__ Xe)
{
    int e = blockIdx.x, s = blockIdx.y;
    int n_e = cnt[e];
    if (n_e == 0) return;
    int tid = threadIdx.x, w = tid >> 6, lane = tid & 63;
    int m16 = lane & 15, q = lane >> 4;
    _Float16* base = Xe + ((size_t)e * NSX + s) * SLAB;
#pragma unroll
    for (int k = 0; k < 4; ++k) {
        int mt = w + k * 4;
        int slot = mt * 16 + m16;
        if (slot >= n_e) slot = n_e - 1;   // clamp: dup of last row
        int t = tok[e * TT + slot];
        const float* src = x + (size_t)t * HD + s * 32 + q * 8;
        f32x4 v0 = *(const f32x4*)src;
        f32x4 v1 = *(const f32x4*)(src + 4);
        half8 h;
        h[0] = (_Float16)v0.x; h[1] = (_Float16)v0.y; h[2] = (_Float16)v0.z; h[3] = (_Float16)v0.w;
        h[4] = (_Float16)v1.x; h[5] = (_Float16)v1.y; h[6] = (_Float16)v1.z; h[7] = (_Float16)v1.w;
        *(half8*)(base + ((size_t)mt * 64 + lane) * 8) = h;
    }
}

// ---------------- Gate/Up ----------------
// grid (NE*2, IDIM/16); 1-wave blocks; tile 128 tokens x 16 cols; depth-3 reg pipeline.
// Per-lane weight load pattern (rows q*8+j, col m16) IS the B-fragment layout:
// cvt f32->f16 in registers, no LDS.
__global__ __launch_bounds__(64, 1) void k_gateup(
    const _Float16* __restrict__ Xe, const float* __restrict__ Wg,
    const float* __restrict__ Wu, const int* __restrict__ cnt,
    _Float16* __restrict__ A)
{
    int e = blockIdx.x >> 1, ttile = blockIdx.x & 1;
    int n_e = cnt[e];
    if (ttile * 128 >= n_e) return;
    int mtbase = ttile * 8;
    int i0 = blockIdx.y * 16;
    int lane = threadIdx.x;
    int m16 = lane & 15, q = lane >> 4;

    const _Float16* abase = Xe + (size_t)e * NSX * SLAB + ((size_t)mtbase * 64 + lane) * 8;
    const float* gp = Wg + ((size_t)e * HD + q * 8) * IDIM + i0 + m16;
    const float* up = Wu + ((size_t)e * HD + q * 8) * IDIM + i0 + m16;

    f32x4 accG[8], accU[8];
#pragma unroll
    for (int mt = 0; mt < 8; ++mt) {
        accG[mt] = (f32x4){0.f, 0.f, 0.f, 0.f};
        accU[mt] = (f32x4){0.f, 0.f, 0.f, 0.f};
    }

    half8 af[3][8];
    float wgr[3][8], wur[3][8];

    constexpr int NK = HD / 32;   // 32
#pragma unroll
    for (int it = 0; it < NK + 2; ++it) {
        if (it < NK) {
            int b = it % 3;
            const _Float16* a_ = abase + (size_t)it * SLAB;
#pragma unroll
            for (int mt = 0; mt < 8; ++mt)
                af[b][mt] = *(const half8*)(a_ + mt * 512);
            const float* g_ = gp + (size_t)it * 32 * IDIM;
            const float* u_ = up + (size_t)it * 32 * IDIM;
#pragma unroll
            for (int j = 0; j < 8; ++j) {
                wgr[b][j] = g_[(size_t)j * IDIM];
                wur[b][j] = u_[(size_t)j * IDIM];
            }
        }
        if (it >= 2) {
            int b = (it - 2) % 3;
            half8 bg, bu;
#pragma unroll
            for (int j = 0; j < 8; ++j) {
                bg[j] = (_Float16)wgr[b][j];
                bu[j] = (_Float16)wur[b][j];
            }
#pragma unroll
            for (int mt = 0; mt < 8; ++mt) {
                accG[mt] = __builtin_amdgcn_mfma_f32_16x16x32_f16(af[b][mt], bg, accG[mt], 0, 0, 0);
                accU[mt] = __builtin_amdgcn_mfma_f32_16x16x32_f16(af[b][mt], bu, accU[mt], 0, 0, 0);
            }
        }
    }

    // store silu(g)*u into A in A-fragment slab order (for k_down's A-operand)
    _Float16* aout = A + ((size_t)e * NSA + (blockIdx.y >> 1)) * SLAB;
    int cj   = m16 & 7;
    int lsub = ((blockIdx.y * 2 + (m16 >> 3)) & 3) * 16;
#pragma unroll
    for (int mt = 0; mt < 8; ++mt) {
#pragma unroll
        for (int r = 0; r < 4; ++r) {
            float g = accG[mt][r], u = accU[mt][r];
            float a = (g / (1.f + expf(-g))) * u;
            int lp = (q * 4 + r) + lsub;
            aout[((size_t)(mtbase + mt) * 64 + lp) * 8 + cj] = (_Float16)a;
        }
    }
}

// ---------------- Down ----------------
// grid (NE*2, HD/16); 1-wave blocks; depth-3 reg pipeline; no LDS.
__global__ __launch_bounds__(64, 2) void k_down(
    const _Float16* __restrict__ A, const float* __restrict__ Wd,
    const int* __restrict__ cnt, const int* __restrict__ tok,
    const float* __restrict__ wl, float* __restrict__ outf)
{
    int e = blockIdx.x >> 1, ttile = blockIdx.x & 1;
    int n_e = cnt[e];
    if (ttile * 128 >= n_e) return;
    int mtbase = ttile * 8;
    int h0 = blockIdx.y * 16;
    int lane = threadIdx.x;
    int m16 = lane & 15, q = lane >> 4;

    const _Float16* abase = A + (size_t)e * NSA * SLAB + ((size_t)mtbase * 64 + lane) * 8;
    const float* dp = Wd + ((size_t)e * IDIM + q * 8) * HD + h0 + m16;

    f32x4 acc[8];
#pragma unroll
    for (int mt = 0; mt < 8; ++mt) acc[mt] = (f32x4){0.f, 0.f, 0.f, 0.f};

    half8 af[3][8];
    float wdr[3][8];

    constexpr int NK = IDIM / 32;  // 16
#pragma unroll
    for (int it = 0; it < NK + 2; ++it) {
        if (it < NK) {
            int b = it % 3;
            const _Float16* a_ = abase + (size_t)it * SLAB;
#pragma unroll
            for (int mt = 0; mt < 8; ++mt)
                af[b][mt] = *(const half8*)(a_ + mt * 512);
            const float* d_ = dp + (size_t)it * 32 * HD;
#pragma unroll
            for (int j = 0; j < 8; ++j)
                wdr[b][j] = d_[(size_t)j * HD];
        }
        if (it >= 2) {
            int b = (it - 2) % 3;
            half8 bd;
#pragma unroll
            for (int j = 0; j < 8; ++j) bd[j] = (_Float16)wdr[b][j];
#pragma unroll
            for (int mt = 0; mt < 8; ++mt)
                acc[mt] = __builtin_amdgcn_mfma_f32_16x16x32_f16(af[b][mt], bd, acc[mt], 0, 0, 0);
        }
    }

    int col = h0 + m16;
#pragma unroll
    for (int mt = 0; mt < 8; ++mt) {
#pragma unroll
        for (int r = 0; r < 4; ++r) {
            int slot = ttile * 128 + mt * 16 + q * 4 + r;
            if (slot < n_e) {
                int t   = tok[(size_t)e * TT + slot];
                float wt = wl[(size_t)e * TT + slot];
                atomicAdd(&outf[(size_t)t * HD + col], wt * acc[mt][r]);
            }
        }
    }
}

extern "C" void kernel_launch(void* const* d_in, const int* in_sizes, int n_in,
                              void* d_out, int out_size, void* d_ws, size_t ws_size,
                              hipStream_t stream) {
    const float* x    = (const float*)d_in[0];
    const float* gw   = (const float*)d_in[1];
    const float* bias = (const float*)d_in[2];
    const float* Wg   = (const float*)d_in[3];
    const float* Wu   = (const float*)d_in[4];
    const float* Wd   = (const float*)d_in[5];
    float* out = (float*)d_out;   // reference output dtype is float32

    char* ws = (char*)d_ws;
    int*      cnt = (int*)(ws + WS_CNT);
    int*      tok = (int*)(ws + WS_TOK);
    float*    wl  = (float*)(ws + WS_WL);
    _Float16* Xe  = (_Float16*)(ws + WS_XE);
    _Float16* A   = (_Float16*)(ws + WS_A);

    hipMemsetAsync(ws, 0, 256, stream);                       // expert counters
    hipMemsetAsync(out, 0, (size_t)TT * HD * 4, stream);      // f32 output accumulator

    k_route<<<TT, 256, 0, stream>>>(x, gw, bias, cnt, tok, wl);
    k_pack<<<dim3(NE, NSX), 256, 0, stream>>>(x, cnt, tok, Xe);
    k_gateup<<<dim3(NE * 2, IDIM / 16), 64, 0, stream>>>(Xe, Wg, Wu, cnt, A);
    k_down<<<dim3(NE * 2, HD / 16), 64, 0, stream>>>(A, Wd, cnt, tok, wl, out);
}